// Round 17
// baseline (123.355 us; speedup 1.0000x reference)
//
#include <hip/hip_runtime.h>
#include <hip/hip_bf16.h>
#include <stdint.h>

#define M_DIM 2048
#define N_DIM 4096
#define K_DIM 4096

#define BM 128
#define BN 256
#define BK 64

typedef __bf16 bf16x8 __attribute__((ext_vector_type(8)));
typedef float f32x4 __attribute__((ext_vector_type(4)));
typedef unsigned short ushort8_t __attribute__((ext_vector_type(8)));

__device__ __forceinline__ unsigned short f32_to_bf16_rne(float f) {
    union { float f; uint32_t u; } cvt;
    cvt.f = f;
    uint32_t u = cvt.u;
    uint32_t r = (u + 0x7fffu + ((u >> 16) & 1u)) >> 16;
    return (unsigned short)r;
}

__device__ __forceinline__ void gload_lds16(const void* g, void* l) {
    __builtin_amdgcn_global_load_lds(
        (__attribute__((address_space(1))) const void*)g,
        (__attribute__((address_space(3))) void*)l,
        16, 0, 0);
}

// ---------------------------------------------------------------------------
// Fused prepass (R13; at the 22.9us compulsory-traffic floor).
// ---------------------------------------------------------------------------
__global__ void prep_kernel(const float* __restrict__ x,
                            unsigned short* __restrict__ xb,
                            const float* __restrict__ W,
                            unsigned short* __restrict__ Wt) {
    __shared__ float tile[64][65];
    const int b = blockIdx.x;
    const int t = threadIdx.x;

    if (b < 4096) {
        const int n0 = (b & 63) * 64;
        const int k0 = (b >> 6) * 64;
        const int tx = t & 15;
        const int ty = t >> 4;

#pragma unroll
        for (int r = 0; r < 4; ++r) {
            int row = ty + 16 * r;
            float4 v = *(const float4*)(W + (size_t)(k0 + row) * N_DIM + n0 + tx * 4);
            tile[row][tx * 4 + 0] = v.x;
            tile[row][tx * 4 + 1] = v.y;
            tile[row][tx * 4 + 2] = v.z;
            tile[row][tx * 4 + 3] = v.w;
        }
        __syncthreads();
#pragma unroll
        for (int r = 0; r < 4; ++r) {
            int nrow = ty + 16 * r;
            ushort4 o;
            o.x = f32_to_bf16_rne(tile[tx * 4 + 0][nrow]);
            o.y = f32_to_bf16_rne(tile[tx * 4 + 1][nrow]);
            o.z = f32_to_bf16_rne(tile[tx * 4 + 2][nrow]);
            o.w = f32_to_bf16_rne(tile[tx * 4 + 3][nrow]);
            *(ushort4*)(Wt + (size_t)(n0 + nrow) * K_DIM + k0 + tx * 4) = o;
        }
    } else {
        const int n8 = M_DIM * K_DIM / 8;
        int i = (b - 4096) * blockDim.x + t;
        const int stride = 2048 * 256;
        for (; i < n8; i += stride) {
            const float4* p = (const float4*)(x + (size_t)i * 8);
            float4 v0 = p[0];
            float4 v1 = p[1];
            ushort8_t o;
            o[0] = f32_to_bf16_rne(v0.x);
            o[1] = f32_to_bf16_rne(v0.y);
            o[2] = f32_to_bf16_rne(v0.z);
            o[3] = f32_to_bf16_rne(v0.w);
            o[4] = f32_to_bf16_rne(v1.x);
            o[5] = f32_to_bf16_rne(v1.y);
            o[6] = f32_to_bf16_rne(v1.z);
            o[7] = f32_to_bf16_rne(v1.w);
            *(ushort8_t*)(xb + (size_t)i * 8) = o;
        }
    }
}

// ---------------------------------------------------------------------------
// GEMM: C[m][n] = sum_k A[m][k] * Bt[n][k] + bias[n]
// R14 structure with A MOVED OUT OF LDS into registers:
//   8 waves = 4 regions (64x128) x 2 kk-roles. Per wave per tile:
//   A = 4 global b128 -> Aa/Ab double-buffer (loaded 1 tile ahead, named
//   sets, rule-20 manual x2 unroll); B = 8 ds_read_b128 from triple-buffered
//   LDS (proven 0-conflict swizzle). LDS pipe drops 96+48 -> 64+32 KB/tile
//   (~1020cyc), BELOW the 1242cyc MFMA floor for the first time.
// Ledger (age order at tile-top is always [stage_B(t), A(t), stage_B(t+1)]):
//   W(t) = vmcnt(4): drains stage_B(t) [RAW for this tile's B, + barrier
//   publishes] AND A(t) regs [issued a full tile ago]; leaves stage_B(t+1)
//   in flight — counted, never 0. lgkm(0) before barrier = WAR for buf
//   (t+2)%3 == (t-1)%3 (its frag reads were this wave's, completed here).
//   Compiler waits before A-use are instant: all younger loads <= 8.
// ---------------------------------------------------------------------------
__global__ __launch_bounds__(512, 2) void gemm_bf16(
    const unsigned short* __restrict__ A,
    const unsigned short* __restrict__ Bt,
    const float* __restrict__ bias,
    float* __restrict__ C) {
    __shared__ __align__(16) char smem[131072];
    // B bufs: smem + buf*32768 (3 x 32 KiB)
    // epilogue partials: smem + region*32768 (4 x 32 KiB, after K-loop)

    const int t      = threadIdx.x;
    const int lane   = t & 63;
    const int wave   = t >> 6;
    const int region = wave >> 1;    // 0..3 : 64x128 output region
    const int kkr    = wave & 1;     // 0/1  : K-half role
    const int rm     = region >> 1;  // 0..1 row block (x64)
    const int rn     = region & 1;   // 0..1 col block (x128)
    const int lrow   = lane & 15;
    const int lhi    = lane >> 4;

    // T1: XCD-aware swizzle (256 WGs, %8==0 -> bijective)
    const int wg  = blockIdx.x;
    const int swz = (wg & 7) * 32 + (wg >> 3);
    const int m0  = (swz >> 4) * BM;
    const int n0  = (swz & 15) * BN;

    // ---- B staging pointers (inverse-swizzled global source, linear LDS) ----
    const int rowc = t >> 3;                  // 0..63
    const int lc   = (t & 7) ^ (rowc & 7);    // swizzled k-slot
    const unsigned short* gB0 = Bt + (size_t)(n0 + rowc) * K_DIM + lc * 8;
    const unsigned short* gB1 = gB0 + (size_t)64  * K_DIM;
    const unsigned short* gB2 = gB0 + (size_t)128 * K_DIM;
    const unsigned short* gB3 = gB0 + (size_t)192 * K_DIM;
    char* dB = smem + t * 16;                 // + buf*32768 (+8192 per unit)

    // ---- A fragment pointers: lane needs row = m0+rm*64+mi*16+lrow,
    //      k = tile*64 + kkr*32 + lhi*8 .. +7 (16B aligned) ----
    const unsigned short* pA[4];
#pragma unroll
    for (int mi = 0; mi < 4; ++mi)
        pA[mi] = A + (size_t)(m0 + rm * 64 + mi * 16 + lrow) * K_DIM
                   + kkr * 32 + lhi * 8;

    f32x4 acc[4][8];  // [mi][nj], this wave's kk-half partial
#pragma unroll
    for (int i = 0; i < 4; ++i)
#pragma unroll
        for (int j = 0; j < 8; ++j) acc[i][j] = (f32x4)0.0f;

    const int NT = K_DIM / BK;  // 64

    // B fragment offsets (row&7 == lrow&7; proven 0-conflict pattern)
    const int rowOffB = (rn * 128 + lrow) * 128;         // + nj*2048, nj 0..7
    const int sK = ((kkr * 4 + lhi) ^ (lrow & 7)) * 16;  // this wave's kk slot

    bf16x8 Aa[4], Ab[4];

    // prologue — issue order fixes the age ledger: stage_B(0), A(0), stage_B(1)
    gload_lds16(gB0, dB);          gload_lds16(gB1, dB + 8192);
    gload_lds16(gB2, dB + 16384);  gload_lds16(gB3, dB + 24576);
#pragma unroll
    for (int mi = 0; mi < 4; ++mi) Aa[mi] = *(const bf16x8*)(pA[mi]);
    gload_lds16(gB0 + BK, dB + 32768);  gload_lds16(gB1 + BK, dB + 40960);
    gload_lds16(gB2 + BK, dB + 49152);  gload_lds16(gB3 + BK, dB + 57344);

    // body: consume tile tau (A in Au, B in sB[tau%3]);
    //       load A(tau+1) -> Al; stage B(tau+2)
    auto body = [&](int tau, bf16x8 (&Au)[4], bf16x8 (&Al)[4]) {
        const size_t kA = (size_t)((tau + 1 < NT) ? tau + 1 : NT - 1) * BK;
        const size_t kB = (size_t)((tau + 2 < NT) ? tau + 2 : NT - 1) * BK;

        // tile-top: counted wait (never 0) + barrier publishes stage_B(tau)
        asm volatile("s_waitcnt vmcnt(4) lgkmcnt(0)" ::: "memory");
        __builtin_amdgcn_s_barrier();
        __builtin_amdgcn_sched_barrier(0);

        const char* bB = smem + (tau % 3) * 32768;
        char* wB = dB + ((tau + 2) % 3) * 32768;

        // ---- P0: nj 0..3 ----
        bf16x8 bf[4];
#pragma unroll
        for (int nj = 0; nj < 4; ++nj)
            bf[nj] = *(const bf16x8*)(bB + rowOffB + nj * 2048 + sK);
        // A(tau+1) -> regs (4 global b128; drained at NEXT tile's vmcnt(4))
#pragma unroll
        for (int mi = 0; mi < 4; ++mi)
            Al[mi] = *(const bf16x8*)(pA[mi] + kA);
        __builtin_amdgcn_s_setprio(1);
#pragma unroll
        for (int mi = 0; mi < 4; ++mi)
#pragma unroll
            for (int nj = 0; nj < 4; ++nj)
                acc[mi][nj] = __builtin_amdgcn_mfma_f32_16x16x32_bf16(
                    Au[mi], bf[nj], acc[mi][nj], 0, 0, 0);
        __builtin_amdgcn_s_setprio(0);

        // ---- P1: nj 4..7 ----
        bf16x8 bg[4];
#pragma unroll
        for (int nj = 0; nj < 4; ++nj)
            bg[nj] = *(const bf16x8*)(bB + rowOffB + (nj + 4) * 2048 + sK);
        gload_lds16(gB0 + kB, wB);
        gload_lds16(gB1 + kB, wB + 8192);
        gload_lds16(gB2 + kB, wB + 16384);
        gload_lds16(gB3 + kB, wB + 24576);
        __builtin_amdgcn_s_setprio(1);
#pragma unroll
        for (int mi = 0; mi < 4; ++mi)
#pragma unroll
            for (int nj = 0; nj < 4; ++nj)
                acc[mi][nj + 4] = __builtin_amdgcn_mfma_f32_16x16x32_bf16(
                    Au[mi], bg[nj], acc[mi][nj + 4], 0, 0, 0);
        __builtin_amdgcn_s_setprio(0);
    };

    for (int tau = 0; tau < NT; tau += 2) {
        body(tau,     Aa, Ab);
        body(tau + 1, Ab, Aa);
    }

    // ---- epilogue: combine kk pair via (dead) LDS, write C + bias ----
    __syncthreads();
    if (kkr == 1) {
#pragma unroll
        for (int mi = 0; mi < 4; ++mi)
#pragma unroll
            for (int nj = 0; nj < 8; ++nj)
                *(f32x4*)(smem + region * 32768 +
                          ((mi * 8 + nj) * 64 + lane) * 16) = acc[mi][nj];
    }
    __syncthreads();
    if (kkr == 0) {
        // C/D layout: col=lane&15, row=(lane>>4)*4+reg
#pragma unroll
        for (int nj = 0; nj < 8; ++nj) {
            int col  = n0 + rn * 128 + nj * 16 + lrow;
            float bv = bias[col];
#pragma unroll
            for (int mi = 0; mi < 4; ++mi) {
                f32x4 p = *(const f32x4*)(smem + region * 32768 +
                                          ((mi * 8 + nj) * 64 + lane) * 16);
                int rbase = m0 + rm * 64 + mi * 16 + lhi * 4;
#pragma unroll
                for (int r = 0; r < 4; ++r) {
                    C[(size_t)(rbase + r) * N_DIM + col] =
                        acc[mi][nj][r] + p[r] + bv;
                }
            }
        }
    }
}

// ---------------------------------------------------------------------------
extern "C" void kernel_launch(void* const* d_in, const int* in_sizes, int n_in,
                              void* d_out, int out_size, void* d_ws, size_t ws_size,
                              hipStream_t stream) {
    const float* x    = (const float*)d_in[0];
    const float* w    = (const float*)d_in[1];
    const float* bias = (const float*)d_in[2];
    float* out        = (float*)d_out;

    unsigned short* xb = (unsigned short*)d_ws;
    unsigned short* wt = (unsigned short*)((char*)d_ws +
                          (size_t)M_DIM * K_DIM * sizeof(unsigned short));

    prep_kernel<<<6144, 256, 0, stream>>>(x, xb, w, wt);

    dim3 ggrid((M_DIM / BM) * (N_DIM / BN));
    gemm_bf16<<<ggrid, 512, 0, stream>>>(xb, wt, bias, out);
}

// Round 18
// 88.955 us; speedup vs baseline: 1.3867x; 1.3867x over previous
//
#include <hip/hip_runtime.h>
#include <hip/hip_bf16.h>
#include <stdint.h>

#define M_DIM 2048
#define N_DIM 4096
#define K_DIM 4096

#define BM 128
#define BN 256
#define BK 64

typedef __bf16 bf16x8 __attribute__((ext_vector_type(8)));
typedef float f32x4 __attribute__((ext_vector_type(4)));
typedef unsigned short ushort8_t __attribute__((ext_vector_type(8)));

__device__ __forceinline__ unsigned short f32_to_bf16_rne(float f) {
    union { float f; uint32_t u; } cvt;
    cvt.f = f;
    uint32_t u = cvt.u;
    uint32_t r = (u + 0x7fffu + ((u >> 16) & 1u)) >> 16;
    return (unsigned short)r;
}

__device__ __forceinline__ void gload_lds16(const void* g, void* l) {
    __builtin_amdgcn_global_load_lds(
        (__attribute__((address_space(1))) const void*)g,
        (__attribute__((address_space(3))) void*)l,
        16, 0, 0);
}

// ---------------------------------------------------------------------------
// Fused prepass (R13; measured 23.5us vs 22.9us compulsory-traffic floor):
// blocks [0,4096) transpose+convert W; blocks [4096,6144) convert x f32->bf16.
// ---------------------------------------------------------------------------
__global__ void prep_kernel(const float* __restrict__ x,
                            unsigned short* __restrict__ xb,
                            const float* __restrict__ W,
                            unsigned short* __restrict__ Wt) {
    __shared__ float tile[64][65];
    const int b = blockIdx.x;
    const int t = threadIdx.x;

    if (b < 4096) {
        const int n0 = (b & 63) * 64;
        const int k0 = (b >> 6) * 64;
        const int tx = t & 15;
        const int ty = t >> 4;

#pragma unroll
        for (int r = 0; r < 4; ++r) {
            int row = ty + 16 * r;
            float4 v = *(const float4*)(W + (size_t)(k0 + row) * N_DIM + n0 + tx * 4);
            tile[row][tx * 4 + 0] = v.x;
            tile[row][tx * 4 + 1] = v.y;
            tile[row][tx * 4 + 2] = v.z;
            tile[row][tx * 4 + 3] = v.w;
        }
        __syncthreads();
#pragma unroll
        for (int r = 0; r < 4; ++r) {
            int nrow = ty + 16 * r;
            ushort4 o;
            o.x = f32_to_bf16_rne(tile[tx * 4 + 0][nrow]);
            o.y = f32_to_bf16_rne(tile[tx * 4 + 1][nrow]);
            o.z = f32_to_bf16_rne(tile[tx * 4 + 2][nrow]);
            o.w = f32_to_bf16_rne(tile[tx * 4 + 3][nrow]);
            *(ushort4*)(Wt + (size_t)(n0 + nrow) * K_DIM + k0 + tx * 4) = o;
        }
    } else {
        const int n8 = M_DIM * K_DIM / 8;
        int i = (b - 4096) * blockDim.x + t;
        const int stride = 2048 * 256;
        for (; i < n8; i += stride) {
            const float4* p = (const float4*)(x + (size_t)i * 8);
            float4 v0 = p[0];
            float4 v1 = p[1];
            ushort8_t o;
            o[0] = f32_to_bf16_rne(v0.x);
            o[1] = f32_to_bf16_rne(v0.y);
            o[2] = f32_to_bf16_rne(v0.z);
            o[3] = f32_to_bf16_rne(v0.w);
            o[4] = f32_to_bf16_rne(v1.x);
            o[5] = f32_to_bf16_rne(v1.y);
            o[6] = f32_to_bf16_rne(v1.z);
            o[7] = f32_to_bf16_rne(v1.w);
            *(ushort8_t*)(xb + (size_t)i * 8) = o;
        }
    }
}

// ---------------------------------------------------------------------------
// GEMM: C[m][n] = sum_k A[m][k] * Bt[n][k] + bias[n]   (R14 — session best,
// reproduced twice at 65.4-66.4us / 1035-1050 TF / MfmaUtil 41-45%)
// 128x256 tile, 8 waves = 4 regions (64x128) x 2 kk-roles (2.67 MFMA/read,
// the single verified win: R9 +12%), triple-buffered LDS, ONE
// vmcnt(6)+lgkm(0)+barrier per K-tile (counted, never 0), proven 0-conflict
// 128B-row swizzle (s = slot ^ (row&7)), hoisted loop-invariant staging
// pointers, setprio around MFMA clusters, compiler-free regions inside the
// tile, kk-combine epilogue through the dead LDS buffers.
// Falsified alternatives (R4,R5,R6,R7,R8,R11,R12,R15,R17): sched_barrier
// pinning, 32x32 MFMA shape, m201 phase rhythms, split-K 256^2, cross-
// barrier reg pipelining, producer/consumer role-split (VGPR spill),
// A-in-registers x2 (vmcnt-counter sharing exposes global latency).
// ---------------------------------------------------------------------------
__global__ __launch_bounds__(512, 2) void gemm_bf16(
    const unsigned short* __restrict__ A,
    const unsigned short* __restrict__ Bt,
    const float* __restrict__ bias,
    float* __restrict__ C) {
    __shared__ __align__(16) char smem[147456];
    // A bufs: smem + buf*16384           (3 x 16 KiB)
    // B bufs: smem + 49152 + buf*32768   (3 x 32 KiB)
    // epilogue partials: smem + region*32768 (4 x 32 KiB, after K-loop)

    const int t      = threadIdx.x;
    const int lane   = t & 63;
    const int wave   = t >> 6;
    const int region = wave >> 1;    // 0..3 : 64x128 output region
    const int kkr    = wave & 1;     // 0/1  : K-half role
    const int rm     = region >> 1;  // 0..1 row block (x64)
    const int rn     = region & 1;   // 0..1 col block (x128)
    const int lrow   = lane & 15;
    const int lhi    = lane >> 4;

    // T1: XCD-aware swizzle (256 WGs, %8==0 -> bijective)
    const int wg  = blockIdx.x;
    const int swz = (wg & 7) * 32 + (wg >> 3);
    const int m0  = (swz >> 4) * BM;
    const int n0  = (swz & 15) * BN;

    // ---- loop-invariant staging pointers (inverse-swizzled global source,
    //      linear LDS dest) ----
    const int rowc = t >> 3;                  // 0..63
    const int lc   = (t & 7) ^ (rowc & 7);    // swizzled k-slot
    const unsigned short* gA0 = A  + (size_t)(m0 + rowc) * K_DIM + lc * 8;
    const unsigned short* gA1 = gA0 + (size_t)64  * K_DIM;   // rows 64..127
    const unsigned short* gB0 = Bt + (size_t)(n0 + rowc) * K_DIM + lc * 8;
    const unsigned short* gB1 = gB0 + (size_t)64  * K_DIM;
    const unsigned short* gB2 = gB0 + (size_t)128 * K_DIM;
    const unsigned short* gB3 = gB0 + (size_t)192 * K_DIM;
    char* dA = smem + t * 16;                 // + buf*16384 (+8192 unit 1)
    char* dB = smem + 49152 + t * 16;         // + buf*32768 (+8192k units)

    f32x4 acc[4][8];  // [mi][nj], this wave's kk-half partial
#pragma unroll
    for (int i = 0; i < 4; ++i)
#pragma unroll
        for (int j = 0; j < 8; ++j) acc[i][j] = (f32x4)0.0f;

    const int NT = K_DIM / BK;  // 64

    // prologue: tiles 0 and 1 fully staged (12 chunks/thread in flight)
    gload_lds16(gA0, dA);               gload_lds16(gA1, dA + 8192);
    gload_lds16(gB0, dB);               gload_lds16(gB1, dB + 8192);
    gload_lds16(gB2, dB + 16384);       gload_lds16(gB3, dB + 24576);
    gload_lds16(gA0 + BK, dA + 16384);  gload_lds16(gA1 + BK, dA + 24576);
    gload_lds16(gB0 + BK, dB + 32768);  gload_lds16(gB1 + BK, dB + 40960);
    gload_lds16(gB2 + BK, dB + 49152);  gload_lds16(gB3 + BK, dB + 57344);

    // fragment offsets (row&7 == lrow&7; proven 0-conflict pattern)
    const int rowOffA = (rm * 64 + lrow) * 128;          // + mi*2048, mi 0..3
    const int rowOffB = (rn * 128 + lrow) * 128;         // + nj*2048, nj 0..7
    const int sK = ((kkr * 4 + lhi) ^ (lrow & 7)) * 16;  // this wave's kk slot

    int bufC = 0, bufS = 2;
    for (int tau = 0; tau < NT; ++tau) {
        const size_t koff = (size_t)((tau + 2 < NT) ? tau + 2 : NT - 1) * BK;

        // one wait + one barrier per K-tile; vmcnt NEVER drains to 0
        asm volatile("s_waitcnt vmcnt(6) lgkmcnt(0)" ::: "memory");
        __builtin_amdgcn_s_barrier();
        __builtin_amdgcn_sched_barrier(0);

        const char* bA = smem + bufC * 16384;
        const char* bB = smem + 49152 + bufC * 32768;
        char* wA = dA + bufS * 16384;
        char* wB = dB + bufS * 32768;

        // ---- P0: nj 0..3 ----
        bf16x8 af[4], bf[4];
#pragma unroll
        for (int mi = 0; mi < 4; ++mi)
            af[mi] = *(const bf16x8*)(bA + rowOffA + mi * 2048 + sK);
#pragma unroll
        for (int nj = 0; nj < 4; ++nj)
            bf[nj] = *(const bf16x8*)(bB + rowOffB + nj * 2048 + sK);
        gload_lds16(gA0 + koff, wA);
        gload_lds16(gA1 + koff, wA + 8192);
        gload_lds16(gB0 + koff, wB);
        __builtin_amdgcn_s_setprio(1);
#pragma unroll
        for (int mi = 0; mi < 4; ++mi)
#pragma unroll
            for (int nj = 0; nj < 4; ++nj)
                acc[mi][nj] = __builtin_amdgcn_mfma_f32_16x16x32_bf16(
                    af[mi], bf[nj], acc[mi][nj], 0, 0, 0);
        __builtin_amdgcn_s_setprio(0);

        // ---- P1: nj 4..7 ----
        bf16x8 bg[4];
#pragma unroll
        for (int nj = 0; nj < 4; ++nj)
            bg[nj] = *(const bf16x8*)(bB + rowOffB + (nj + 4) * 2048 + sK);
        gload_lds16(gB1 + koff, wB + 8192);
        gload_lds16(gB2 + koff, wB + 16384);
        gload_lds16(gB3 + koff, wB + 24576);
        __builtin_amdgcn_s_setprio(1);
#pragma unroll
        for (int mi = 0; mi < 4; ++mi)
#pragma unroll
            for (int nj = 0; nj < 4; ++nj)
                acc[mi][nj + 4] = __builtin_amdgcn_mfma_f32_16x16x32_bf16(
                    af[mi], bg[nj], acc[mi][nj + 4], 0, 0, 0);
        __builtin_amdgcn_s_setprio(0);

        bufC = (bufC == 2) ? 0 : bufC + 1;
        bufS = (bufS == 2) ? 0 : bufS + 1;
    }

    // ---- epilogue: combine kk pair via (dead) LDS, write C + bias ----
    __syncthreads();
    if (kkr == 1) {
#pragma unroll
        for (int mi = 0; mi < 4; ++mi)
#pragma unroll
            for (int nj = 0; nj < 8; ++nj)
                *(f32x4*)(smem + region * 32768 +
                          ((mi * 8 + nj) * 64 + lane) * 16) = acc[mi][nj];
    }
    __syncthreads();
    if (kkr == 0) {
        // C/D layout: col=lane&15, row=(lane>>4)*4+reg
#pragma unroll
        for (int nj = 0; nj < 8; ++nj) {
            int col  = n0 + rn * 128 + nj * 16 + lrow;
            float bv = bias[col];
#pragma unroll
            for (int mi = 0; mi < 4; ++mi) {
                f32x4 p = *(const f32x4*)(smem + region * 32768 +
                                          ((mi * 8 + nj) * 64 + lane) * 16);
                int rbase = m0 + rm * 64 + mi * 16 + lhi * 4;
#pragma unroll
                for (int r = 0; r < 4; ++r) {
                    C[(size_t)(rbase + r) * N_DIM + col] =
                        acc[mi][nj][r] + p[r] + bv;
                }
            }
        }
    }
}

// ---------------------------------------------------------------------------
extern "C" void kernel_launch(void* const* d_in, const int* in_sizes, int n_in,
                              void* d_out, int out_size, void* d_ws, size_t ws_size,
                              hipStream_t stream) {
    const float* x    = (const float*)d_in[0];
    const float* w    = (const float*)d_in[1];
    const float* bias = (const float*)d_in[2];
    float* out        = (float*)d_out;

    unsigned short* xb = (unsigned short*)d_ws;
    unsigned short* wt = (unsigned short*)((char*)d_ws +
                          (size_t)M_DIM * K_DIM * sizeof(unsigned short));

    prep_kernel<<<6144, 256, 0, stream>>>(x, xb, w, wt);

    dim3 ggrid((M_DIM / BM) * (N_DIM / BN));
    gemm_bf16<<<ggrid, 512, 0, stream>>>(xb, wt, bias, out);
}